// Round 1
// baseline (479.500 us; speedup 1.0000x reference)
//
#include <hip/hip_runtime.h>
#include <hip/hip_bf16.h>
#include <math.h>

// Problem constants
#define B_SZ 4096
#define P_HID 1024
#define H_HID 512
#define MAX_P 128
#define MAX_HE 42
#define E_MAX 8128            // C(128,2)
#define E_MAX4 2032           // E_MAX/4

// ---------------------------------------------------------------------------
// Generic tiled fp32 GEMM:  C = act(A[M,K] @ W[K,N] + bias[N])
// BM in {64,128}, BN=64, BK=16, 256 threads, thread tile TM x 4.
// M % BM == 0 and K % BK == 0 are assumed (true for all our shapes).
// N tail handled with guards (N=42 case).
// ---------------------------------------------------------------------------
template<int BM, bool GELU_ACT>
__global__ __launch_bounds__(256) void gemm_bias(
    const float* __restrict__ A, const float* __restrict__ W,
    const float* __restrict__ bias, float* __restrict__ C,
    int M, int N, int K)
{
    constexpr int BN = 64, BK = 16;
    constexpr int TM = BM / 16;       // 8 (BM=128) or 4 (BM=64)
    constexpr int TN = 4;
    constexpr int ALOADS = TM / 4;    // 2 or 1 float4 A-loads per thread

    __shared__ float As[BK][BM + 4];  // [k][m], +4 pad keeps 16B alignment
    __shared__ float Bs[BK][BN];      // [k][n]

    const int tid = threadIdx.x;
    const int tx  = tid & 15;         // n-group
    const int ty  = tid >> 4;         // m-group
    const int bm  = blockIdx.y * BM;
    const int bn  = blockIdx.x * BN;

    // A-load mapping: (row, 4 consecutive k)
    const int aRow = tid >> 2;        // 0..63
    const int aK   = (tid & 3) << 2;  // 0,4,8,12
    // B-load mapping: (k, 4 consecutive n)
    const int bK  = tid >> 4;         // 0..15
    const int bN0 = (tid & 15) << 2;  // 0..60

    const bool nvec = ((N & 3) == 0);

    float acc[TM][TN];
#pragma unroll
    for (int r = 0; r < TM; ++r)
#pragma unroll
        for (int j = 0; j < TN; ++j) acc[r][j] = 0.f;

    for (int k0 = 0; k0 < K; k0 += BK) {
        float4 aval[ALOADS];
#pragma unroll
        for (int u = 0; u < ALOADS; ++u)
            aval[u] = *(const float4*)&A[(size_t)(bm + aRow + 64 * u) * K + (k0 + aK)];

        float bval[4];
        if (nvec && (bn + bN0 + 3 < N)) {
            float4 t = *(const float4*)&W[(size_t)(k0 + bK) * N + bn + bN0];
            bval[0] = t.x; bval[1] = t.y; bval[2] = t.z; bval[3] = t.w;
        } else {
#pragma unroll
            for (int j = 0; j < 4; ++j) {
                int n = bn + bN0 + j;
                bval[j] = (n < N) ? W[(size_t)(k0 + bK) * N + n] : 0.f;
            }
        }

        __syncthreads();
#pragma unroll
        for (int u = 0; u < ALOADS; ++u) {
            As[aK + 0][aRow + 64 * u] = aval[u].x;
            As[aK + 1][aRow + 64 * u] = aval[u].y;
            As[aK + 2][aRow + 64 * u] = aval[u].z;
            As[aK + 3][aRow + 64 * u] = aval[u].w;
        }
        *(float4*)&Bs[bK][bN0] = make_float4(bval[0], bval[1], bval[2], bval[3]);
        __syncthreads();

#pragma unroll
        for (int k = 0; k < BK; ++k) {
            float av[TM], bv[TN];
#pragma unroll
            for (int r = 0; r < TM; ++r) av[r] = As[k][ty * TM + r];
#pragma unroll
            for (int j = 0; j < TN; ++j) bv[j] = Bs[k][tx * TN + j];
#pragma unroll
            for (int r = 0; r < TM; ++r)
#pragma unroll
                for (int j = 0; j < TN; ++j)
                    acc[r][j] += av[r] * bv[j];
        }
    }

    // epilogue: bias (+ exact GELU) + store
#pragma unroll
    for (int r = 0; r < TM; ++r) {
        const int m = bm + ty * TM + r;
        float vals[TN];
#pragma unroll
        for (int j = 0; j < TN; ++j) {
            int n = bn + tx * TN + j;
            float v = acc[r][j] + ((n < N) ? bias[n] : 0.f);
            if (GELU_ACT) v = 0.5f * v * (1.f + erff(v * 0.70710678118654752f));
            vals[j] = v;
        }
        if (nvec && (bn + tx * TN + 3 < N)) {
            *(float4*)&C[(size_t)m * N + bn + tx * TN] =
                make_float4(vals[0], vals[1], vals[2], vals[3]);
        } else {
#pragma unroll
            for (int j = 0; j < TN; ++j) {
                int n = bn + tx * TN + j;
                if (n < N) C[(size_t)m * N + n] = vals[j];
            }
        }
    }
}

// ---------------------------------------------------------------------------
// Gumbel-hard mask + per-row count.
// hard0 = (l + g0) > (-l + g1)  (softmax is monotone; tau=1 > 0)
// One block (64 threads = 1 wave) per batch row.
// ---------------------------------------------------------------------------
__global__ __launch_bounds__(64) void mask_count(
    const float* __restrict__ logits, const float* __restrict__ g,
    float* __restrict__ out_mask, float* __restrict__ out_n,
    int* __restrict__ ws_n, int L)
{
    const int b = blockIdx.x;
    const int t = threadIdx.x;
    float cnt = 0.f;
    for (int i = t; i < L; i += 64) {
        size_t idx = (size_t)b * L + i;
        float l  = logits[idx];
        float g0 = g[idx * 2 + 0];
        float g1 = g[idx * 2 + 1];
        float hard = ((l + g0) > (g1 - l)) ? 1.f : 0.f;
        out_mask[idx] = hard;
        cnt += hard;
    }
#pragma unroll
    for (int off = 32; off > 0; off >>= 1) cnt += __shfl_down(cnt, off, 64);
    if (t == 0) {
        out_n[b] = cnt;
        if (ws_n) ws_n[b] = (int)cnt;
    }
}

// ---------------------------------------------------------------------------
// edge_index: lexicographic triu pairs (i,j), i<j, of MAX_P=128.
// off(i) = (255*i - i*i)/2 pairs precede first-index i.
// ---------------------------------------------------------------------------
__device__ __forceinline__ int tri_off(int i) { return (i * (255 - i)) >> 1; }

__global__ __launch_bounds__(256) void edge_index_kernel(
    float* __restrict__ out_ei, int* __restrict__ ws_jj)
{
    int e = blockIdx.x * 256 + threadIdx.x;
    if (e >= E_MAX) return;
    int i = (int)((255.0 - sqrt(65025.0 - 8.0 * (double)e)) * 0.5);
    if (i < 0) i = 0;
    if (i > 126) i = 126;
    while (i > 0 && tri_off(i) > e) --i;
    while (i < 126 && tri_off(i + 1) <= e) ++i;
    int j = i + 1 + (e - tri_off(i));
    out_ei[e] = (float)i;
    out_ei[E_MAX + e] = (float)j;
    ws_jj[e] = j;
}

// ---------------------------------------------------------------------------
// edge_valid[b,e] = jj[e] < n_particles[b], written as float 0/1, float4 wide.
// ---------------------------------------------------------------------------
__global__ __launch_bounds__(256) void edge_valid_kernel(
    const int* __restrict__ ws_jj, const int* __restrict__ ws_n,
    float* __restrict__ out, int total4)
{
    int idx = blockIdx.x * 256 + threadIdx.x;
    if (idx >= total4) return;
    int b = idx / E_MAX4;
    int q = idx - b * E_MAX4;
    int4 j4 = ((const int4*)ws_jj)[q];
    int n = ws_n[b];
    float4 v;
    v.x = (j4.x < n) ? 1.f : 0.f;
    v.y = (j4.y < n) ? 1.f : 0.f;
    v.z = (j4.z < n) ? 1.f : 0.f;
    v.w = (j4.w < n) ? 1.f : 0.f;
    ((float4*)out)[idx] = v;
}

// ---------------------------------------------------------------------------
extern "C" void kernel_launch(void* const* d_in, const int* in_sizes, int n_in,
                              void* d_out, int out_size, void* d_ws, size_t ws_size,
                              hipStream_t stream)
{
    const float* particle_h  = (const float*)d_in[0];
    // d_in[1] = edge_h — unused by the reference
    const float* hyperedge_h = (const float*)d_in[2];
    const float* g_p  = (const float*)d_in[3];
    const float* g_h  = (const float*)d_in[4];
    const float* W1_p = (const float*)d_in[5];
    const float* b1_p = (const float*)d_in[6];
    const float* W2_p = (const float*)d_in[7];
    const float* b2_p = (const float*)d_in[8];
    const float* W1_h = (const float*)d_in[9];
    const float* b1_h = (const float*)d_in[10];
    const float* W2_h = (const float*)d_in[11];
    const float* b2_h = (const float*)d_in[12];

    // Output layout (all float32, concatenated flat in return order)
    float* out = (float*)d_out;
    float* out_pmask = out;                                   // 4096*128
    float* out_np    = out_pmask + (size_t)B_SZ * MAX_P;      // 4096
    float* out_ei    = out_np + B_SZ;                         // 2*8128
    float* out_ev    = out_ei + 2 * E_MAX;                    // 4096*8128
    float* out_hmask = out_ev + (size_t)B_SZ * E_MAX;         // 4096*42
    float* out_nh    = out_hmask + (size_t)B_SZ * MAX_HE;     // 4096

    // Workspace layout (~28 MB)
    float* ws    = (float*)d_ws;
    float* hid_p = ws;                                        // 4096*1024
    float* hid_h = hid_p + (size_t)B_SZ * P_HID;              // 4096*512
    float* log_p = hid_h + (size_t)B_SZ * H_HID;              // 4096*128
    float* log_h = log_p + (size_t)B_SZ * MAX_P;              // 4096*42
    int*   ws_np = (int*)(log_h + (size_t)B_SZ * MAX_HE);     // 4096
    int*   ws_jj = ws_np + B_SZ;                              // 8128

    // --- particle branch ---
    // H_p = GELU(particle_h @ W1_p + b1_p): M=4096,N=1024,K=1024
    gemm_bias<128, true><<<dim3(1024 / 64, 4096 / 128), 256, 0, stream>>>(
        particle_h, W1_p, b1_p, hid_p, B_SZ, P_HID, P_HID);
    // logits_p = H_p @ W2_p + b2_p: M=4096,N=128,K=1024
    gemm_bias<64, false><<<dim3(128 / 64, 4096 / 64), 256, 0, stream>>>(
        hid_p, W2_p, b2_p, log_p, B_SZ, MAX_P, P_HID);
    mask_count<<<B_SZ, 64, 0, stream>>>(log_p, g_p, out_pmask, out_np, ws_np, MAX_P);

    // --- hyperedge branch ---
    gemm_bias<128, true><<<dim3(512 / 64, 4096 / 128), 256, 0, stream>>>(
        hyperedge_h, W1_h, b1_h, hid_h, B_SZ, H_HID, H_HID);
    gemm_bias<64, false><<<dim3(1, 4096 / 64), 256, 0, stream>>>(
        hid_h, W2_h, b2_h, log_h, B_SZ, MAX_HE, H_HID);
    mask_count<<<B_SZ, 64, 0, stream>>>(log_h, g_h, out_hmask, out_nh, nullptr, MAX_HE);

    // --- topology ---
    edge_index_kernel<<<(E_MAX + 255) / 256, 256, 0, stream>>>(out_ei, ws_jj);
    edge_valid_kernel<<<(B_SZ * E_MAX4 + 255) / 256, 256, 0, stream>>>(
        ws_jj, ws_np, out_ev, B_SZ * E_MAX4);
}

// Round 2
// 311.785 us; speedup vs baseline: 1.5379x; 1.5379x over previous
//
#include <hip/hip_runtime.h>
#include <hip/hip_bf16.h>
#include <math.h>

typedef __bf16 bf16_t;
typedef bf16_t bf16x8 __attribute__((ext_vector_type(8)));
typedef bf16_t bf16x4 __attribute__((ext_vector_type(4)));
typedef float f32x4 __attribute__((ext_vector_type(4)));
typedef unsigned int u32;

#define B_SZ 4096
#define P_HID 1024
#define H_HID 512
#define MAX_P 128
#define MAX_HE 42
#define HE_PAD 64
#define E_MAX 8128
#define E_MAX4 2032

// ---------------------------------------------------------------------------
// async global->LDS 16B copy: per-lane global src, wave-uniform LDS base,
// HW dest = base + lane*16  [m97 pattern]
// ---------------------------------------------------------------------------
__device__ __forceinline__ void async_cp16(const bf16_t* g, bf16_t* l) {
    __builtin_amdgcn_global_load_lds(
        (const __attribute__((address_space(1))) u32*)g,
        (__attribute__((address_space(3))) u32*)l, 16, 0, 0);
}

__device__ __forceinline__ float gelu_exact(float v) {
    return 0.5f * v * (1.f + erff(v * 0.70710678118654752f));
}

// ---------------------------------------------------------------------------
// Split-bf16 MFMA GEMM:  C = A[M,K] @ B[K,N] (+bias, +GELU) with
// A given as pre-split bf16 planes Ahi/Alo [M][K], B as pre-split
// TRANSPOSED planes BThi/BTlo [N][K].
// acc = Ahi*Bhi + Ahi*Blo + Alo*Bhi  (3 MFMA per data element)
// MODE 0: epilogue v = gelu(acc+bias); write split bf16 planes Chi/Clo [M][N]
// MODE 1: epilogue atomicAdd fp32 into Cf (bias pre-initialized; split-K)
// Tiles: BM x BN per block, BK=32, 256 threads = 4 waves in 2x2 wave grid.
// ---------------------------------------------------------------------------
template<int BM, int BN, int MODE>
__global__ __launch_bounds__(256, 2) void gemm_sp(
    const bf16_t* __restrict__ Ahi, const bf16_t* __restrict__ Alo,
    const bf16_t* __restrict__ BThi, const bf16_t* __restrict__ BTlo,
    const float* __restrict__ bias,
    float* __restrict__ Cf, bf16_t* __restrict__ Chi, bf16_t* __restrict__ Clo,
    int M, int N, int K, int kchunk)
{
    constexpr int MT = BM / 32;            // m-subtiles per wave (wave rows = BM/2)
    constexpr int NT = BN / 32;            // n-subtiles per wave
    constexpr int OPS_A = BM / 16;         // 16-row async ops per A plane
    constexpr int OPS_B = BN / 16;
    constexpr int NOPS = 2 * OPS_A + 2 * OPS_B;

    __shared__ __align__(16) bf16_t smem[(2 * BM + 2 * BN) * 32];
    bf16_t* const As0 = smem;
    bf16_t* const As1 = smem + BM * 32;
    bf16_t* const Bs0 = smem + 2 * BM * 32;
    bf16_t* const Bs1 = smem + 2 * BM * 32 + BN * 32;

    const int tid  = threadIdx.x;
    const int lane = tid & 63;
    const int wid  = tid >> 6;
    const int wm   = wid & 1;
    const int wn   = wid >> 1;
    const int bm   = blockIdx.y * BM;
    const int bn   = blockIdx.x * BN;
    const int k0   = blockIdx.z * kchunk;

    const int srow = lane >> 2;            // staging row within 16-row op
    const int scol = (lane & 3) * 8;       // staging k-offset (bf16)

    f32x4 acc[MT][NT];
#pragma unroll
    for (int i = 0; i < MT; ++i)
#pragma unroll
        for (int j = 0; j < NT; ++j)
            acc[i][j] = (f32x4){0.f, 0.f, 0.f, 0.f};

    const bf16_t* const gA0 = Ahi  + (size_t)bm * K;
    const bf16_t* const gA1 = Alo  + (size_t)bm * K;
    const bf16_t* const gB0 = BThi + (size_t)bn * K;
    const bf16_t* const gB1 = BTlo + (size_t)bn * K;

    const int fr = lane & 15;              // fragment row/col within 16
    const int fq = lane >> 4;              // k-quad

    for (int kt = k0; kt < k0 + kchunk; kt += 32) {
        __syncthreads();                   // previous iter's frag reads done
        // ---- async staging: NOPS wave-ops round-robin over 4 waves ----
#pragma unroll
        for (int o = 0; o < NOPS; ++o) {
            if ((o & 3) != wid) continue;
            const bf16_t* gsrc;
            bf16_t* lbase;
            int q;
            if (o < OPS_A)               { q = o;                 gsrc = gA0; lbase = As0; }
            else if (o < 2 * OPS_A)      { q = o - OPS_A;         gsrc = gA1; lbase = As1; }
            else if (o < 2 * OPS_A + OPS_B) { q = o - 2 * OPS_A;  gsrc = gB0; lbase = Bs0; }
            else                         { q = o - 2 * OPS_A - OPS_B; gsrc = gB1; lbase = Bs1; }
            async_cp16(gsrc + (size_t)(q * 16 + srow) * K + kt + scol,
                       lbase + q * 16 * 32);
        }
        __syncthreads();                   // compiler drains vmcnt before barrier

        // ---- fragment loads (ds_read_b128) ----
        bf16x8 ah[MT], al[MT], bh[NT], bl[NT];
#pragma unroll
        for (int i = 0; i < MT; ++i) {
            const int row = wm * (BM / 2) + i * 16 + fr;
            ah[i] = *(const bf16x8*)(As0 + row * 32 + fq * 8);
            al[i] = *(const bf16x8*)(As1 + row * 32 + fq * 8);
        }
#pragma unroll
        for (int j = 0; j < NT; ++j) {
            const int row = wn * (BN / 2) + j * 16 + fr;
            bh[j] = *(const bf16x8*)(Bs0 + row * 32 + fq * 8);
            bl[j] = *(const bf16x8*)(Bs1 + row * 32 + fq * 8);
        }
        // ---- 3-term split MFMA ----
#pragma unroll
        for (int i = 0; i < MT; ++i)
#pragma unroll
            for (int j = 0; j < NT; ++j) {
                acc[i][j] = __builtin_amdgcn_mfma_f32_16x16x32_bf16(ah[i], bh[j], acc[i][j], 0, 0, 0);
                acc[i][j] = __builtin_amdgcn_mfma_f32_16x16x32_bf16(ah[i], bl[j], acc[i][j], 0, 0, 0);
                acc[i][j] = __builtin_amdgcn_mfma_f32_16x16x32_bf16(al[i], bh[j], acc[i][j], 0, 0, 0);
            }
    }

    // ---- epilogue ----  C/D layout: col = lane&15, row = (lane>>4)*4 + reg
#pragma unroll
    for (int i = 0; i < MT; ++i)
#pragma unroll
        for (int j = 0; j < NT; ++j) {
            const int col  = bn + wn * (BN / 2) + j * 16 + fr;
            const int row0 = bm + wm * (BM / 2) + i * 16 + fq * 4;
            if (MODE == 0) {
                const float bj = bias[col];
#pragma unroll
                for (int r = 0; r < 4; ++r) {
                    float v = gelu_exact(acc[i][j][r] + bj);
                    bf16_t h = (bf16_t)v;
                    bf16_t l = (bf16_t)(v - (float)h);
                    const size_t off = (size_t)(row0 + r) * N + col;
                    Chi[off] = h;
                    Clo[off] = l;
                }
            } else {
#pragma unroll
                for (int r = 0; r < 4; ++r)
                    atomicAdd(&Cf[(size_t)(row0 + r) * N + col], acc[i][j][r]);
            }
        }
}

// ---------------------------------------------------------------------------
// fp32 -> split bf16 planes, elementwise (activations), float4-wide
// ---------------------------------------------------------------------------
__global__ __launch_bounds__(256) void split_rows(
    const float* __restrict__ x, bf16_t* __restrict__ hi, bf16_t* __restrict__ lo, int n4)
{
    int i = blockIdx.x * 256 + threadIdx.x;
    if (i >= n4) return;
    float4 v = ((const float4*)x)[i];
    float vv[4] = {v.x, v.y, v.z, v.w};
    bf16x4 h, l;
#pragma unroll
    for (int r = 0; r < 4; ++r) {
        bf16_t hh = (bf16_t)vv[r];
        h[r] = hh;
        l[r] = (bf16_t)(vv[r] - (float)hh);
    }
    ((bf16x4*)hi)[i] = h;
    ((bf16x4*)lo)[i] = l;
}

// ---------------------------------------------------------------------------
// Weight prep: W[K][N] fp32 -> transposed split planes T{hi,lo}[Npad][K] bf16
// (rows n >= N zero-filled). 32x32 LDS tile, grid (Npad/32, K/32).
// ---------------------------------------------------------------------------
__global__ __launch_bounds__(256) void wsplit_t(
    const float* __restrict__ W, bf16_t* __restrict__ Thi, bf16_t* __restrict__ Tlo,
    int K, int N)
{
    __shared__ float t[32][33];
    const int n0 = blockIdx.x * 32, k0 = blockIdx.y * 32;
    const int tx = threadIdx.x & 31, ty = threadIdx.x >> 5;  // ty: 0..7
    for (int r = ty; r < 32; r += 8) {
        const int n = n0 + tx;
        t[r][tx] = (n < N) ? W[(size_t)(k0 + r) * N + n] : 0.f;
    }
    __syncthreads();
    for (int r = ty; r < 32; r += 8) {
        const float x = t[tx][r];          // = W[k0+tx][n0+r]
        bf16_t h = (bf16_t)x;
        bf16_t l = (bf16_t)(x - (float)h);
        const size_t off = (size_t)(n0 + r) * K + k0 + tx;
        Thi[off] = h;
        Tlo[off] = l;
    }
}

// ---------------------------------------------------------------------------
// Pre-fill logits buffers with bias (split-K GEMM2 atomically accumulates).
// ---------------------------------------------------------------------------
__global__ __launch_bounds__(256) void init_logits(
    const float* __restrict__ b2p, const float* __restrict__ b2h,
    float* __restrict__ logp, float* __restrict__ logh)
{
    const int i = blockIdx.x * 256 + threadIdx.x;
    const int NP = B_SZ * MAX_P;
    if (i < NP) {
        logp[i] = b2p[i & (MAX_P - 1)];
    } else {
        const int r = i - NP;
        if (r < B_SZ * HE_PAD) {
            const int c = r & (HE_PAD - 1);
            logh[r] = (c < MAX_HE) ? b2h[c] : 0.f;
        }
    }
}

// ---------------------------------------------------------------------------
// Gumbel-hard mask + count.  hard0 = (l+g0) > (g1-l)  (softmax monotone)
// logits have row stride ls (>= L).
// ---------------------------------------------------------------------------
__global__ __launch_bounds__(64) void mask_count(
    const float* __restrict__ logits, const float* __restrict__ g,
    float* __restrict__ out_mask, float* __restrict__ out_n,
    int* __restrict__ ws_n, int L, int ls)
{
    const int b = blockIdx.x;
    const int t = threadIdx.x;
    float cnt = 0.f;
    for (int i = t; i < L; i += 64) {
        const float l  = logits[(size_t)b * ls + i];
        const float g0 = g[((size_t)b * L + i) * 2 + 0];
        const float g1 = g[((size_t)b * L + i) * 2 + 1];
        const float hard = ((l + g0) > (g1 - l)) ? 1.f : 0.f;
        out_mask[(size_t)b * L + i] = hard;
        cnt += hard;
    }
#pragma unroll
    for (int off = 32; off > 0; off >>= 1) cnt += __shfl_down(cnt, off, 64);
    if (t == 0) {
        out_n[b] = cnt;
        if (ws_n) ws_n[b] = (int)cnt;
    }
}

// ---------------------------------------------------------------------------
// edge_index (triu pairs of 128) + jj table
// ---------------------------------------------------------------------------
__device__ __forceinline__ int tri_off(int i) { return (i * (255 - i)) >> 1; }

__global__ __launch_bounds__(256) void edge_index_kernel(
    float* __restrict__ out_ei, int* __restrict__ ws_jj)
{
    int e = blockIdx.x * 256 + threadIdx.x;
    if (e >= E_MAX) return;
    int i = (int)((255.0 - sqrt(65025.0 - 8.0 * (double)e)) * 0.5);
    if (i < 0) i = 0;
    if (i > 126) i = 126;
    while (i > 0 && tri_off(i) > e) --i;
    while (i < 126 && tri_off(i + 1) <= e) ++i;
    int j = i + 1 + (e - tri_off(i));
    out_ei[e] = (float)i;
    out_ei[E_MAX + e] = (float)j;
    ws_jj[e] = j;
}

// ---------------------------------------------------------------------------
// edge_valid[b,e] = jj[e] < n_particles[b], float4-wide
// ---------------------------------------------------------------------------
__global__ __launch_bounds__(256) void edge_valid_kernel(
    const int* __restrict__ ws_jj, const int* __restrict__ ws_n,
    float* __restrict__ out, int total4)
{
    int idx = blockIdx.x * 256 + threadIdx.x;
    if (idx >= total4) return;
    int b = idx / E_MAX4;
    int q = idx - b * E_MAX4;
    int4 j4 = ((const int4*)ws_jj)[q];
    int n = ws_n[b];
    float4 v;
    v.x = (j4.x < n) ? 1.f : 0.f;
    v.y = (j4.y < n) ? 1.f : 0.f;
    v.z = (j4.z < n) ? 1.f : 0.f;
    v.w = (j4.w < n) ? 1.f : 0.f;
    ((float4*)out)[idx] = v;
}

// ---------------------------------------------------------------------------
extern "C" void kernel_launch(void* const* d_in, const int* in_sizes, int n_in,
                              void* d_out, int out_size, void* d_ws, size_t ws_size,
                              hipStream_t stream)
{
    const float* particle_h  = (const float*)d_in[0];
    const float* hyperedge_h = (const float*)d_in[2];
    const float* g_p  = (const float*)d_in[3];
    const float* g_h  = (const float*)d_in[4];
    const float* W1_p = (const float*)d_in[5];
    const float* b1_p = (const float*)d_in[6];
    const float* W2_p = (const float*)d_in[7];
    const float* b2_p = (const float*)d_in[8];
    const float* W1_h = (const float*)d_in[9];
    const float* b1_h = (const float*)d_in[10];
    const float* W2_h = (const float*)d_in[11];
    const float* b2_h = (const float*)d_in[12];

    // Output layout (flat fp32, return order)
    float* out = (float*)d_out;
    float* out_pmask = out;                                   // 4096*128
    float* out_np    = out_pmask + (size_t)B_SZ * MAX_P;      // 4096
    float* out_ei    = out_np + B_SZ;                         // 2*8128
    float* out_ev    = out_ei + 2 * E_MAX;                    // 4096*8128
    float* out_hmask = out_ev + (size_t)B_SZ * E_MAX;         // 4096*42
    float* out_nh    = out_hmask + (size_t)B_SZ * MAX_HE;     // 4096

    // Workspace layout (~57 MB)
    char* w = (char*)d_ws;
    bf16_t* pA_hi  = (bf16_t*)w;                    w += (size_t)B_SZ * P_HID * 2;
    bf16_t* pA_lo  = (bf16_t*)w;                    w += (size_t)B_SZ * P_HID * 2;
    bf16_t* hA_hi  = (bf16_t*)w;                    w += (size_t)B_SZ * H_HID * 2;
    bf16_t* hA_lo  = (bf16_t*)w;                    w += (size_t)B_SZ * H_HID * 2;
    bf16_t* hidp_hi = (bf16_t*)w;                   w += (size_t)B_SZ * P_HID * 2;
    bf16_t* hidp_lo = (bf16_t*)w;                   w += (size_t)B_SZ * P_HID * 2;
    bf16_t* hidh_hi = (bf16_t*)w;                   w += (size_t)B_SZ * H_HID * 2;
    bf16_t* hidh_lo = (bf16_t*)w;                   w += (size_t)B_SZ * H_HID * 2;
    bf16_t* W1pT_hi = (bf16_t*)w;                   w += (size_t)P_HID * P_HID * 2;
    bf16_t* W1pT_lo = (bf16_t*)w;                   w += (size_t)P_HID * P_HID * 2;
    bf16_t* W2pT_hi = (bf16_t*)w;                   w += (size_t)MAX_P * P_HID * 2;
    bf16_t* W2pT_lo = (bf16_t*)w;                   w += (size_t)MAX_P * P_HID * 2;
    bf16_t* W1hT_hi = (bf16_t*)w;                   w += (size_t)H_HID * H_HID * 2;
    bf16_t* W1hT_lo = (bf16_t*)w;                   w += (size_t)H_HID * H_HID * 2;
    bf16_t* W2hT_hi = (bf16_t*)w;                   w += (size_t)HE_PAD * H_HID * 2;
    bf16_t* W2hT_lo = (bf16_t*)w;                   w += (size_t)HE_PAD * H_HID * 2;
    float*  log_p   = (float*)w;                    w += (size_t)B_SZ * MAX_P * 4;
    float*  log_h   = (float*)w;                    w += (size_t)B_SZ * HE_PAD * 4;
    int*    ws_np   = (int*)w;                      w += B_SZ * 4;
    int*    ws_jj   = (int*)w;

    // ---- prep: split activations, transpose+split weights, bias-init logits
    split_rows<<<(B_SZ * P_HID / 4 + 255) / 256, 256, 0, stream>>>(
        particle_h, pA_hi, pA_lo, B_SZ * P_HID / 4);
    split_rows<<<(B_SZ * H_HID / 4 + 255) / 256, 256, 0, stream>>>(
        hyperedge_h, hA_hi, hA_lo, B_SZ * H_HID / 4);
    wsplit_t<<<dim3(P_HID / 32, P_HID / 32), 256, 0, stream>>>(W1_p, W1pT_hi, W1pT_lo, P_HID, P_HID);
    wsplit_t<<<dim3(MAX_P / 32, P_HID / 32), 256, 0, stream>>>(W2_p, W2pT_hi, W2pT_lo, P_HID, MAX_P);
    wsplit_t<<<dim3(H_HID / 32, H_HID / 32), 256, 0, stream>>>(W1_h, W1hT_hi, W1hT_lo, H_HID, H_HID);
    wsplit_t<<<dim3(HE_PAD / 32, H_HID / 32), 256, 0, stream>>>(W2_h, W2hT_hi, W2hT_lo, H_HID, MAX_HE);
    init_logits<<<(B_SZ * (MAX_P + HE_PAD) + 255) / 256, 256, 0, stream>>>(
        b2_p, b2_h, log_p, log_h);

    // ---- particle branch ----
    // GEMM1_p: [4096,1024]x[1024,1024] gelu -> split hid planes
    gemm_sp<64, 128, 0><<<dim3(P_HID / 128, B_SZ / 64, 1), 256, 0, stream>>>(
        pA_hi, pA_lo, W1pT_hi, W1pT_lo, b1_p, nullptr, hidp_hi, hidp_lo,
        B_SZ, P_HID, P_HID, P_HID);
    // GEMM2_p: [4096,1024]x[1024,128], split-K=4, atomic into bias-filled log_p
    gemm_sp<64, 128, 1><<<dim3(1, B_SZ / 64, 4), 256, 0, stream>>>(
        hidp_hi, hidp_lo, W2pT_hi, W2pT_lo, nullptr, log_p, nullptr, nullptr,
        B_SZ, MAX_P, P_HID, P_HID / 4);
    mask_count<<<B_SZ, 64, 0, stream>>>(log_p, g_p, out_pmask, out_np, ws_np, MAX_P, MAX_P);

    // ---- hyperedge branch ----
    gemm_sp<64, 64, 0><<<dim3(H_HID / 64, B_SZ / 64, 1), 256, 0, stream>>>(
        hA_hi, hA_lo, W1hT_hi, W1hT_lo, b1_h, nullptr, hidh_hi, hidh_lo,
        B_SZ, H_HID, H_HID, H_HID);
    gemm_sp<64, 64, 1><<<dim3(1, B_SZ / 64, 4), 256, 0, stream>>>(
        hidh_hi, hidh_lo, W2hT_hi, W2hT_lo, nullptr, log_h, nullptr, nullptr,
        B_SZ, HE_PAD, H_HID, H_HID / 4);
    mask_count<<<B_SZ, 64, 0, stream>>>(log_h, g_h, out_hmask, out_nh, nullptr, MAX_HE, HE_PAD);

    // ---- topology ----
    edge_index_kernel<<<(E_MAX + 255) / 256, 256, 0, stream>>>(out_ei, ws_jj);
    edge_valid_kernel<<<(B_SZ * E_MAX4 + 255) / 256, 256, 0, stream>>>(
        ws_jj, ws_np, out_ev, B_SZ * E_MAX4);
}